// Round 1
// baseline (608.877 us; speedup 1.0000x reference)
//
#include <hip/hip_runtime.h>
#include <hip/hip_bf16.h>

#define HIDDEN 2048
#define INNER  4096
#define NHH    64
#define HEADD  64
#define BCC    128
#define BB     128

typedef __attribute__((ext_vector_type(4))) float f32x4;
typedef __attribute__((ext_vector_type(8))) short short8;
typedef unsigned short ushort;
typedef unsigned int uint;
typedef __attribute__((ext_vector_type(4))) ushort u16x4;

// d_out offsets in floats (return order: out, x_cs, b_cs, c_cs, ssm_new)
#define OFF_OUT 0
#define OFF_XCS 262144
#define OFF_BCS 1835008
#define OFF_CCS 1884160
#define OFF_SSM 1933312

__device__ __forceinline__ ushort f2bf(float f){
  uint u = __float_as_uint(f);
  u += 0x7FFFu + ((u >> 16) & 1u);   // RNE
  return (ushort)(u >> 16);
}

// ---------------------------------------------------------------- cvt t->bf16
__global__ __launch_bounds__(256) void cvtk(const float* __restrict__ t,
                                            ushort* __restrict__ tb){
  int e = (blockIdx.x * 256 + threadIdx.x) * 4;
  f32x4 v = *(const f32x4*)(t + e);
  u16x4 o;
  o[0] = f2bf(v[0]); o[1] = f2bf(v[1]); o[2] = f2bf(v[2]); o[3] = f2bf(v[3]);
  *(u16x4*)(tb + e) = o;
}

// ---------------------------------------------------------------- MFMA GEMM
// C[128, N] = A[128, K](bf16) @ W[N, K](f32, cvt on the fly)^T
// block: 256 thr = 4 waves; tile: M=128 (all rows), BN=64, BK=64.
// wave w computes rows [w*32, w*32+32) x 64 cols; acc[2][4] 16x16 frags.
__device__ __forceinline__ void gemm_body(
    const ushort* __restrict__ A, const float* __restrict__ W,
    float* __restrict__ C, ushort* Bs,
    int N, int K, int ncol0, int kt0, int kt1, bool atomic)
{
  const int tid  = threadIdx.x;
  const int wave = tid >> 6;
  const int lane = tid & 63;
  const int l15  = lane & 15;
  const int l4   = lane >> 4;

  f32x4 acc[2][4];
#pragma unroll
  for (int i = 0; i < 2; i++)
#pragma unroll
    for (int j = 0; j < 4; j++) acc[i][j] = (f32x4){0.f, 0.f, 0.f, 0.f};

  const ushort* Arow = A + (size_t)(wave * 32 + l15) * K + l4 * 8;
  const int sn  = tid >> 2;            // staged row (n) 0..63
  const int skq = (tid & 3) * 16;      // k quarter
  const float* Wrow = W + (size_t)(ncol0 + sn) * K + skq;
  ushort* wdst = Bs + sn * 72 + skq;   // padded stride 72 (2-way max conflict)

  for (int kt = kt0; kt < kt1; ++kt){
    const float* src = Wrow + kt * 64;
    f32x4 v0 = *(const f32x4*)(src);
    f32x4 v1 = *(const f32x4*)(src + 4);
    f32x4 v2 = *(const f32x4*)(src + 8);
    f32x4 v3 = *(const f32x4*)(src + 12);
    __syncthreads();                    // prev iter's reads of Bs done
    union { short8 s; ushort u[8]; } p0, p1;
    p0.u[0]=f2bf(v0[0]); p0.u[1]=f2bf(v0[1]); p0.u[2]=f2bf(v0[2]); p0.u[3]=f2bf(v0[3]);
    p0.u[4]=f2bf(v1[0]); p0.u[5]=f2bf(v1[1]); p0.u[6]=f2bf(v1[2]); p0.u[7]=f2bf(v1[3]);
    p1.u[0]=f2bf(v2[0]); p1.u[1]=f2bf(v2[1]); p1.u[2]=f2bf(v2[2]); p1.u[3]=f2bf(v2[3]);
    p1.u[4]=f2bf(v3[0]); p1.u[5]=f2bf(v3[1]); p1.u[6]=f2bf(v3[2]); p1.u[7]=f2bf(v3[3]);
    *(short8*)(wdst)     = p0.s;
    *(short8*)(wdst + 8) = p1.s;
    __syncthreads();

    const int k0 = kt * 64;
    short8 af0 = *(const short8*)(Arow + k0);               // mrep0, kf0
    short8 af1 = *(const short8*)(Arow + k0 + 32);          // mrep0, kf1
    short8 af2 = *(const short8*)(Arow + (size_t)16 * K + k0);        // mrep1, kf0
    short8 af3 = *(const short8*)(Arow + (size_t)16 * K + k0 + 32);   // mrep1, kf1
#pragma unroll
    for (int nr = 0; nr < 4; nr++){
      const ushort* bp = Bs + (nr * 16 + l15) * 72 + l4 * 8;
      short8 bf0 = *(const short8*)(bp);
      short8 bf1 = *(const short8*)(bp + 32);
      acc[0][nr] = __builtin_amdgcn_mfma_f32_16x16x32_bf16(af0, bf0, acc[0][nr], 0, 0, 0);
      acc[1][nr] = __builtin_amdgcn_mfma_f32_16x16x32_bf16(af2, bf0, acc[1][nr], 0, 0, 0);
      acc[0][nr] = __builtin_amdgcn_mfma_f32_16x16x32_bf16(af1, bf1, acc[0][nr], 0, 0, 0);
      acc[1][nr] = __builtin_amdgcn_mfma_f32_16x16x32_bf16(af3, bf1, acc[1][nr], 0, 0, 0);
    }
  }

  // epilogue: C/D frag: col = lane&15, row = (lane>>4)*4 + j  [m89 verified]
#pragma unroll
  for (int mr = 0; mr < 2; mr++)
#pragma unroll
    for (int nr = 0; nr < 4; nr++){
      int row = wave * 32 + mr * 16 + l4 * 4;
      int col = ncol0 + nr * 16 + l15;
      float* cp = C + (size_t)row * N + col;
#pragma unroll
      for (int j = 0; j < 4; j++){
        if (atomic) atomicAdd(cp + (size_t)j * N, acc[mr][nr][j]);
        else        cp[(size_t)j * N] = acc[mr][nr][j];
      }
    }
}

__global__ __launch_bounds__(256) void gemm5(const ushort* __restrict__ A,
    const float* __restrict__ Win, const float* __restrict__ Wz,
    const float* __restrict__ Wb,  const float* __restrict__ Wc,
    const float* __restrict__ Wdt,
    float* __restrict__ xp, float* __restrict__ zp, float* __restrict__ bp,
    float* __restrict__ cp, float* __restrict__ dtp)
{
  __shared__ ushort Bs[64 * 72];
  int id = blockIdx.x;
  const float* W; float* C; int N; int nt;
  if      (id < 64)  { W = Win; C = xp;  N = 4096; nt = id; }
  else if (id < 128) { W = Wz;  C = zp;  N = 4096; nt = id - 64; }
  else if (id < 130) { W = Wb;  C = bp;  N = 128;  nt = id - 128; }
  else if (id < 132) { W = Wc;  C = cp;  N = 128;  nt = id - 130; }
  else               { W = Wdt; C = dtp; N = 64;   nt = 0; }
  gemm_body(A, W, C, Bs, N, 2048, nt * 64, 0, 32, false);
}

__global__ __launch_bounds__(256) void gemm_out_k(const ushort* __restrict__ yn,
    const float* __restrict__ Wout, float* __restrict__ out)
{
  __shared__ ushort Bs[64 * 72];
  int kt0 = blockIdx.y * 16;                 // split-K: 4 x 16 kt-steps
  gemm_body(yn, Wout, out, Bs, 2048, 4096, blockIdx.x * 64, kt0, kt0 + 16, true);
}

// ---------------------------------------------------------------- conv + act
__global__ __launch_bounds__(256) void convk(
    const float* __restrict__ xpre, const float* __restrict__ bpre,
    const float* __restrict__ cpre, const float* __restrict__ dtpre,
    const float* __restrict__ xcs, const float* __restrict__ bcs,
    const float* __restrict__ ccs,
    const float* __restrict__ cxw, const float* __restrict__ cxb,
    const float* __restrict__ cbw, const float* __restrict__ cbb,
    const float* __restrict__ ccw, const float* __restrict__ ccb,
    const float* __restrict__ bdt, const float* __restrict__ av,
    float* __restrict__ xact, float* __restrict__ bact, float* __restrict__ cact,
    float* __restrict__ dtact, float* __restrict__ decay,
    float* __restrict__ dout)
{
  int e = blockIdx.x * 256 + threadIdx.x;
  if (e < 524288){                     // x path: [128, 4096]
    int i = e & 4095;
    float s0 = xcs[(size_t)e*3], s1 = xcs[(size_t)e*3+1], s2 = xcs[(size_t)e*3+2];
    float xp = xpre[e];
    float v = s0*cxw[i*4] + s1*cxw[i*4+1] + s2*cxw[i*4+2] + xp*cxw[i*4+3] + cxb[i];
    xact[e] = v / (1.f + expf(-v));
    float* o = dout + OFF_XCS + (size_t)e*3;
    o[0] = s1; o[1] = s2; o[2] = xp;
  } else if (e < 540672){              // b path: [128, 128]
    int f = e - 524288; int i = f & 127;
    float s0 = bcs[f*3], s1 = bcs[f*3+1], s2 = bcs[f*3+2];
    float bv = bpre[f];
    float v = s0*cbw[i*4] + s1*cbw[i*4+1] + s2*cbw[i*4+2] + bv*cbw[i*4+3] + cbb[i];
    bact[f] = v / (1.f + expf(-v));
    float* o = dout + OFF_BCS + (size_t)f*3;
    o[0] = s1; o[1] = s2; o[2] = bv;
  } else if (e < 557056){              // c path: [128, 128]
    int g = e - 540672; int i = g & 127;
    float s0 = ccs[g*3], s1 = ccs[g*3+1], s2 = ccs[g*3+2];
    float cv = cpre[g];
    float v = s0*ccw[i*4] + s1*ccw[i*4+1] + s2*ccw[i*4+2] + cv*ccw[i*4+3] + ccb[i];
    cact[g] = v / (1.f + expf(-v));
    float* o = dout + OFF_CCS + (size_t)g*3;
    o[0] = s1; o[1] = s2; o[2] = cv;
  } else if (e < 565248){              // dt path: [128, 64] -> softplus, decay
    int h2 = e - 557056; int n = h2 & 63;
    float v = dtpre[h2] + bdt[n];
    float sp = (v > 20.f) ? v : log1pf(expf(v));
    dtact[h2] = sp;
    decay[h2] = expf(av[n] * sp);
  }
}

// ---------------------------------------------------------------- SSM update
// block = (b, n); 64x128 f32 tile: new = decay*old + dt*b[c]*x[h]; y = c . new + d*x
__global__ __launch_bounds__(256) void ssm_k(
    const float* __restrict__ sstate, const float* __restrict__ bact,
    const float* __restrict__ cact,  const float* __restrict__ xact,
    const float* __restrict__ dtact, const float* __restrict__ decayv,
    const float* __restrict__ dvec,  float* __restrict__ sout,
    float* __restrict__ y)
{
  int blk = blockIdx.x;
  int b = blk >> 6, n = blk & 63;
  __shared__ float c_sh[128], bdt_sh[128], x_sh[64];
  int tid = threadIdx.x;
  float dt  = dtact[blk];
  float dec = decayv[blk];
  float dn  = dvec[n];
  if (tid < 128){
    c_sh[tid]   = cact[b*128 + tid];
    bdt_sh[tid] = dt * bact[b*128 + tid];
  } else if (tid < 192){
    x_sh[tid - 128] = xact[(size_t)b*4096 + n*64 + (tid - 128)];
  }
  __syncthreads();
  size_t base4 = (size_t)blk * 2048;          // in float4 units (8192 floats)
  const f32x4* src = (const f32x4*)sstate + base4;
  f32x4* dst = (f32x4*)sout + base4;
#pragma unroll
  for (int p = 0; p < 8; p++){
    int idx4 = p * 256 + tid;
    int h  = idx4 >> 5;                        // 32 float4 per row of 128
    int c0 = (idx4 & 31) * 4;
    float xv = x_sh[h];
    f32x4 o = src[idx4];
    f32x4 nv;
    nv[0] = dec*o[0] + bdt_sh[c0+0]*xv;
    nv[1] = dec*o[1] + bdt_sh[c0+1]*xv;
    nv[2] = dec*o[2] + bdt_sh[c0+2]*xv;
    nv[3] = dec*o[3] + bdt_sh[c0+3]*xv;
    dst[idx4] = nv;
    float acc = c_sh[c0]*nv[0] + c_sh[c0+1]*nv[1] + c_sh[c0+2]*nv[2] + c_sh[c0+3]*nv[3];
    acc += __shfl_xor(acc, 16, 32);
    acc += __shfl_xor(acc, 8, 32);
    acc += __shfl_xor(acc, 4, 32);
    acc += __shfl_xor(acc, 2, 32);
    acc += __shfl_xor(acc, 1, 32);
    if ((tid & 31) == 0)
      y[(size_t)b*4096 + n*64 + h] = acc + dn * xv;
  }
}

// ---------------------------------------------------------------- gate + RMS
__global__ __launch_bounds__(256) void normk(const float* __restrict__ y,
    const float* __restrict__ zp, const float* __restrict__ nw,
    ushort* __restrict__ yn)
{
  int b = blockIdx.x, tid = threadIdx.x;
  __shared__ float wsum[4];
  const float* yr = y  + (size_t)b*4096;
  const float* zr = zp + (size_t)b*4096;
  float uv[16];
  float ss = 0.f;
#pragma unroll
  for (int q = 0; q < 16; q++){
    int i = tid + q * 256;
    float zv = zr[i];
    float uu = yr[i] * (zv / (1.f + expf(-zv)));
    uv[q] = uu;
    ss += uu * uu;
  }
  ss += __shfl_xor(ss, 32); ss += __shfl_xor(ss, 16); ss += __shfl_xor(ss, 8);
  ss += __shfl_xor(ss, 4);  ss += __shfl_xor(ss, 2);  ss += __shfl_xor(ss, 1);
  if ((tid & 63) == 0) wsum[tid >> 6] = ss;
  __syncthreads();
  float total = wsum[0] + wsum[1] + wsum[2] + wsum[3];
  float scale = rsqrtf(total * (1.f / 4096.f) + 1e-5f);
  ushort* yo = yn + (size_t)b*4096;
#pragma unroll
  for (int q = 0; q < 16; q++){
    int i = tid + q * 256;
    yo[i] = f2bf(uv[q] * scale * nw[i]);
  }
}

// ---------------------------------------------------------------- launch
extern "C" void kernel_launch(void* const* d_in, const int* in_sizes, int n_in,
                              void* d_out, int out_size, void* d_ws, size_t ws_size,
                              hipStream_t stream) {
  const float* t    = (const float*)d_in[0];
  const float* xcs  = (const float*)d_in[1];
  const float* bcs  = (const float*)d_in[2];
  const float* ccs  = (const float*)d_in[3];
  const float* ssm  = (const float*)d_in[4];
  const float* W_in = (const float*)d_in[5];
  const float* W_z  = (const float*)d_in[6];
  const float* W_b  = (const float*)d_in[7];
  const float* W_c  = (const float*)d_in[8];
  const float* W_dt = (const float*)d_in[9];
  const float* b_dt = (const float*)d_in[10];
  const float* cxw  = (const float*)d_in[11];
  const float* cxb  = (const float*)d_in[12];
  const float* cbw  = (const float*)d_in[13];
  const float* cbb  = (const float*)d_in[14];
  const float* ccw  = (const float*)d_in[15];
  const float* ccb  = (const float*)d_in[16];
  const float* a_   = (const float*)d_in[17];
  const float* d_   = (const float*)d_in[18];
  const float* nw   = (const float*)d_in[19];
  const float* W_out= (const float*)d_in[20];

  char* ws = (char*)d_ws;
  ushort* t_bf  = (ushort*)(ws);                // 512 KB
  float*  x_pre = (float*)(ws + 524288);        // 2 MB
  float*  z_pre = (float*)(ws + 2621440);       // 2 MB
  float*  b_pre = (float*)(ws + 4718592);       // 64 KB
  float*  c_pre = (float*)(ws + 4784128);       // 64 KB
  float*  dt_pre= (float*)(ws + 4849664);       // 32 KB
  float*  x_act = (float*)(ws + 4882432);       // 2 MB
  float*  b_act = (float*)(ws + 6979584);       // 64 KB
  float*  c_act = (float*)(ws + 7045120);       // 64 KB
  float*  dt_act= (float*)(ws + 7110656);       // 32 KB
  float*  decay = (float*)(ws + 7143424);       // 32 KB
  float*  y     = (float*)(ws + 7176192);       // 2 MB
  ushort* yn    = (ushort*)(ws + 9273344);      // 1 MB

  float* out = (float*)d_out;

  hipMemsetAsync(out, 0, 262144 * sizeof(float), stream);   // for split-K atomics
  cvtk<<<256, 256, 0, stream>>>(t, t_bf);
  gemm5<<<133, 256, 0, stream>>>(t_bf, W_in, W_z, W_b, W_c, W_dt,
                                 x_pre, z_pre, b_pre, c_pre, dt_pre);
  convk<<<2208, 256, 0, stream>>>(x_pre, b_pre, c_pre, dt_pre, xcs, bcs, ccs,
                                  cxw, cxb, cbw, cbb, ccw, ccb, b_dt, a_,
                                  x_act, b_act, c_act, dt_act, decay, out);
  ssm_k<<<8192, 256, 0, stream>>>(ssm, b_act, c_act, x_act, dt_act, decay, d_,
                                  out + OFF_SSM, y);
  normk<<<128, 256, 0, stream>>>(y, z_pre, nw, yn);
  gemm_out_k<<<dim3(32, 4), 256, 0, stream>>>(yn, W_out, out);
}